// Round 4
// baseline (643.329 us; speedup 1.0000x reference)
//
#include <hip/hip_runtime.h>
#include <hip/hip_bf16.h>

// Flash attention fwd, 1 head, B=64, S=1024, D=256. fp32 in/out (confirmed
// round 3: detection picked the fp32 path). Compute: bf16 MFMA 16x16x32,
// fp32 accum. Block = 256 thr (4 waves); block tile = 128 Q rows (M=32/wave,
// two 16-row m-tiles share K/V fragments). Grid 8x64 = 512 = 2 blocks/CU.
// KV tile 64x256 staged in LDS with granule-XOR swizzle:
//   elem (r,c) -> r*264 + (((c>>3) ^ ((r>>3)&7))<<3) + (c&7)
// -> V-side scalar column reads 2-way (free), S-side b128 reads uniform,
//    staging writes conflict-free, 16B alignment kept (264*2=528=33*16).

#define NB   64
#define NQ   1024
#define NKV  1024
#define DM   256
#define BQ   128    // q rows per block (32 per wave)
#define BK   64     // kv rows per tile
#define KROW 264    // ks row stride (elems); 528B rows, 16B aligned
#define PPAD 72     // ps row stride (elems)
#define LOG2E   1.4426950408889634f
#define NEG_BIG (-1e30f)

typedef __attribute__((ext_vector_type(8))) short  bf16x8;   // 8 bf16 = 4 VGPRs
typedef __attribute__((ext_vector_type(4))) float  floatx4;

__device__ __forceinline__ ushort f2bf(float f) {
  __hip_bfloat16 h = __float2bfloat16(f);
  return *(ushort*)&h;
}

// swizzled LDS index for the KV tile (r = kv row 0..63, c = feature 0..255)
__device__ __forceinline__ int ksw(int r, int c) {
  return r * KROW + ((((c >> 3) ^ ((r >> 3) & 7)) << 3) | (c & 7));
}

__global__ __launch_bounds__(256, 2) void attn_fwd(
    const float* __restrict__ q, const float* __restrict__ kv,
    float* __restrict__ out)
{
  __shared__ ushort ks[BK * KROW];          // 33.8 KB swizzled KV tile
  __shared__ ushort ps[4 * 32 * PPAD];      // 18.4 KB per-wave P staging

  const int tid   = threadIdx.x;
  const int wave  = tid >> 6;
  const int lane  = tid & 63;
  const int quad  = lane >> 4;
  const int l16   = lane & 15;
  const int batch = blockIdx.y;
  const int q0    = blockIdx.x * BQ + wave * 32;

  // Q fragments, A-layout, two m-tiles: qf[mt][kb][j] = Q[q0+mt*16+l16][kb*32+quad*8+j]
  bf16x8 qf[2][8];
#pragma unroll
  for (int mt = 0; mt < 2; ++mt) {
    const float* qp = q + ((size_t)(batch * NQ + q0 + mt * 16 + l16)) * DM + quad * 8;
#pragma unroll
    for (int kb = 0; kb < 8; ++kb) {
      float4 f0 = *(const float4*)(qp + kb * 32);
      float4 f1 = *(const float4*)(qp + kb * 32 + 4);
      bf16x8 o; ushort* op = (ushort*)&o;
      op[0]=f2bf(f0.x); op[1]=f2bf(f0.y); op[2]=f2bf(f0.z); op[3]=f2bf(f0.w);
      op[4]=f2bf(f1.x); op[5]=f2bf(f1.y); op[6]=f2bf(f1.z); op[7]=f2bf(f1.w);
      qf[mt][kb] = o;
    }
  }

  floatx4 acc[2][16];   // acc[mt][nt][r] = O[mt*16 + quad*4+r][nt*16+l16]
#pragma unroll
  for (int mt = 0; mt < 2; ++mt)
#pragma unroll
    for (int i = 0; i < 16; ++i) acc[mt][i] = (floatx4){0.f, 0.f, 0.f, 0.f};
  float m_i[2][4], l_i[2][4];
#pragma unroll
  for (int mt = 0; mt < 2; ++mt)
#pragma unroll
    for (int r = 0; r < 4; ++r) { m_i[mt][r] = NEG_BIG; l_i[mt][r] = 0.f; }

  for (int kt = 0; kt < NKV / BK; ++kt) {
    __syncthreads();  // protect ks/ps from previous iteration's readers
    // ---- stage kv tile 64x256 fp32 -> bf16 LDS (swizzled) ----
    {
      const float* src = kv + ((size_t)(batch * NKV + kt * BK)) * DM;
#pragma unroll
      for (int i = 0; i < 8; ++i) {
        int v = tid + i * 256;      // 2048 8-elem chunks
        int r = v >> 5;             // 32 chunks per row
        int c = (v & 31) << 3;
        const float* sp = src + r * DM + c;
        float4 f0 = *(const float4*)(sp);
        float4 f1 = *(const float4*)(sp + 4);
        bf16x8 o; ushort* op = (ushort*)&o;
        op[0]=f2bf(f0.x); op[1]=f2bf(f0.y); op[2]=f2bf(f0.z); op[3]=f2bf(f0.w);
        op[4]=f2bf(f1.x); op[5]=f2bf(f1.y); op[6]=f2bf(f1.z); op[7]=f2bf(f1.w);
        *(bf16x8*)&ks[ksw(r, c)] = o;   // c%8==0: one full granule, b128 write
      }
    }
    __syncthreads();

    // ---- S = (Q @ K^T) * scale : 32x64 per wave; K b-frags shared across mt ----
    floatx4 s[2][4];
#pragma unroll
    for (int mt = 0; mt < 2; ++mt)
#pragma unroll
      for (int nt = 0; nt < 4; ++nt) s[mt][nt] = (floatx4){0.f, 0.f, 0.f, 0.f};
#pragma unroll
    for (int nt = 0; nt < 4; ++nt) {
#pragma unroll
      for (int kb = 0; kb < 8; ++kb) {
        bf16x8 bfr = *(const bf16x8*)&ks[ksw(nt * 16 + l16, kb * 32 + quad * 8)];
        s[0][nt] = __builtin_amdgcn_mfma_f32_16x16x32_bf16(qf[0][kb], bfr, s[0][nt], 0, 0, 0);
        s[1][nt] = __builtin_amdgcn_mfma_f32_16x16x32_bf16(qf[1][kb], bfr, s[1][nt], 0, 0, 0);
      }
    }

    // ---- online softmax + P write, per m-tile ----
    ushort* pw = ps + wave * 32 * PPAD;
#pragma unroll
    for (int mt = 0; mt < 2; ++mt) {
#pragma unroll
      for (int r = 0; r < 4; ++r) {
        float s0 = s[mt][0][r] * 0.0625f, s1 = s[mt][1][r] * 0.0625f;
        float s2 = s[mt][2][r] * 0.0625f, s3 = s[mt][3][r] * 0.0625f;
        float mx = fmaxf(fmaxf(s0, s1), fmaxf(s2, s3));
        mx = fmaxf(mx, __shfl_xor(mx, 1));
        mx = fmaxf(mx, __shfl_xor(mx, 2));
        mx = fmaxf(mx, __shfl_xor(mx, 4));
        mx = fmaxf(mx, __shfl_xor(mx, 8));
        float mnew  = fmaxf(m_i[mt][r], mx);
        float alpha = exp2f(fmaxf((m_i[mt][r] - mnew) * LOG2E, -126.f));
        float p0 = exp2f((s0 - mnew) * LOG2E);
        float p1 = exp2f((s1 - mnew) * LOG2E);
        float p2 = exp2f((s2 - mnew) * LOG2E);
        float p3 = exp2f((s3 - mnew) * LOG2E);
        float rs = p0 + p1 + p2 + p3;
        rs += __shfl_xor(rs, 1);
        rs += __shfl_xor(rs, 2);
        rs += __shfl_xor(rs, 4);
        rs += __shfl_xor(rs, 8);
        l_i[mt][r] = l_i[mt][r] * alpha + rs;
        m_i[mt][r] = mnew;
#pragma unroll
        for (int nt = 0; nt < 16; ++nt) acc[mt][nt][r] *= alpha;
        const int row = (mt * 16 + quad * 4 + r) * PPAD + l16;
        pw[row +  0] = f2bf(p0);
        pw[row + 16] = f2bf(p1);
        pw[row + 32] = f2bf(p2);
        pw[row + 48] = f2bf(p3);
      }
    }
    __syncthreads();

    // ---- P a-frags ----
    bf16x8 pf[2][2];
#pragma unroll
    for (int mt = 0; mt < 2; ++mt)
#pragma unroll
      for (int kf = 0; kf < 2; ++kf)
        pf[mt][kf] = *(const bf16x8*)&pw[(mt * 16 + l16) * PPAD + kf * 32 + quad * 8];

    // ---- O += P @ V : V b-frags shared across mt (scalar reads, 2-way after swizzle) ----
#pragma unroll
    for (int nt = 0; nt < 16; ++nt) {
#pragma unroll
      for (int kf = 0; kf < 2; ++kf) {
        bf16x8 vf;
#pragma unroll
        for (int j = 0; j < 8; ++j)
          ((ushort*)&vf)[j] = ks[ksw(kf * 32 + quad * 8 + j, nt * 16 + l16)];
        acc[0][nt] = __builtin_amdgcn_mfma_f32_16x16x32_bf16(pf[0][kf], vf, acc[0][nt], 0, 0, 0);
        acc[1][nt] = __builtin_amdgcn_mfma_f32_16x16x32_bf16(pf[1][kf], vf, acc[1][nt], 0, 0, 0);
      }
    }
  }

  // ---- epilogue: O / l, fp32 stores ----
#pragma unroll
  for (int mt = 0; mt < 2; ++mt) {
    float inv[4];
#pragma unroll
    for (int r = 0; r < 4; ++r) inv[r] = 1.f / l_i[mt][r];
    float* ob = out + ((size_t)(batch * NQ + q0 + mt * 16 + quad * 4)) * DM + l16;
#pragma unroll
    for (int nt = 0; nt < 16; ++nt)
#pragma unroll
      for (int r = 0; r < 4; ++r)
        ob[(size_t)r * DM + nt * 16] = acc[mt][nt][r] * inv[r];
  }
}

extern "C" void kernel_launch(void* const* d_in, const int* in_sizes, int n_in,
                              void* d_out, int out_size, void* d_ws, size_t ws_size,
                              hipStream_t stream) {
  const float* q  = (const float*)d_in[0];
  const float* kv = (const float*)d_in[1];
  float* out      = (float*)d_out;
  dim3 grid(NQ / BQ, NB);
  attn_fwd<<<grid, dim3(256), 0, stream>>>(q, kv, out);
}